// Round 6
// baseline (779.043 us; speedup 1.0000x reference)
//
#include <hip/hip_runtime.h>
#include <cstdint>
#include <cstddef>

typedef unsigned short u16;
typedef unsigned int   u32;
typedef _Float16       f16;
typedef u16  u16x4 __attribute__((ext_vector_type(4)));
typedef u16  u16x8 __attribute__((ext_vector_type(8)));
typedef f16  f16x8 __attribute__((ext_vector_type(8)));
typedef float f32x4 __attribute__((ext_vector_type(4)));

static __device__ __forceinline__ u16 f2h(float f){
  f16 h = (f16)f;
  return __builtin_bit_cast(u16, h);
}
static __device__ __forceinline__ float h2f(u16 b){
  f16 h = __builtin_bit_cast(f16, b);
  return (float)h;
}

// ============================================================================
// PACKED FRAGMENT LAYOUT (no swizzle — there is no LDS anywhere in the GEMM):
// For a 64-row block of a K-major fp16 matrix, chunk (blk, t) holds rows
// blk*64..+63, cols t*32..+31, as u16 index:
//   chunk_base = (blk*NT + t)*2048
//   + q*512 + (rr*4 + gg)*8 + e      q=(row&63)>>4, rr=row&15, gg=(col>>3)&3, e=col&7
// A wave reading fragment q (16 rows x 32 cols) with per-lane offset
// la = (l16*4 + quad)*8 issues ONE fully-coalesced 1KB global_load_dwordx4:
// lane (l16,quad) gets rows l16, cols quad*8..+8 = exactly the MFMA A/B frag.
// pack_x uses 128-row chunks (q in 0..7), stride 4096 u16 per t.
// ============================================================================

// ---- transpose 4 weight matrices (fp32 in) -> packed fp16 chunks ----
__global__ void transpose_weights(const float* __restrict__ lw, const float* __restrict__ w1,
                                  const float* __restrict__ w2, const float* __restrict__ w3,
                                  u16* __restrict__ lwP, u16* __restrict__ w1P,
                                  u16* __restrict__ w2P, u16* __restrict__ w3P,
                                  int G, int Gpad)
{
  __shared__ float t[32][33];
  int z = blockIdx.z;
  const float* in = (z==0)? lw : (z==1)? w1 : (z==2)? w2 : w3;
  u16* out        = (z==0)? lwP: (z==1)? w1P: (z==2)? w2P: w3P;
  int R   = (z==0)? G : 256;
  int ldo = (z==0)? Gpad : 256;
  int NTz = ldo >> 5;
  int by = blockIdx.y, bx = blockIdx.x;
  if (by*32 >= R && z != 0) return;       // z==0 must still zero-fill pad cols
  int tid = threadIdx.x;
  #pragma unroll
  for (int k=0;k<4;k++){
    int p = tid + k*256; int r = p>>5, c = p&31;
    int gr = by*32 + r;
    t[r][c] = (gr < R) ? in[gr*256 + bx*32 + c] : 0.f;
  }
  __syncthreads();
  #pragma unroll
  for (int k=0;k<4;k++){
    int p = tid + k*256; int r = p>>5, c = p&31;
    int n  = bx*32 + r;                   // output row (0..255)
    int kk = by*32 + c;                   // output col (k dim)
    if (kk < ldo){
      int idx = ((n>>6)*NTz + (kk>>5))*2048 + ((n>>4)&3)*512
              + ((n&15)*4 + ((kk>>3)&3))*8 + (kk&7);
      out[idx] = f2h(t[c][r]);
    }
  }
}

// ---- pack x (fp32 [N x G]) -> packed fp16 128-row chunks ----
// chunk (m, t): u16 idx = (m*32 + t)*4096 + q*512 + (rr*4 + gg)*8 + e,
//   q=(row&127)>>4, rr=row&15, gg=(col>>3)&3, e=col&7. Zero-padded past G/N.
__global__ __launch_bounds__(256) void pack_x(
    const float* __restrict__ x, u16* __restrict__ P, int N, int G)
{
  int tid = threadIdx.x;
  int r   = blockIdx.x*8 + (tid>>5);      // global row
  int c8l = tid & 31;
  int m = r >> 7, R = r & 127, q = R >> 4, rr = R & 15;
  bool rv = r < N;
  const float* xr = x + (size_t)r*G;
  #pragma unroll
  for (int p=0;p<4;p++){
    int c8 = c8l + p*32;                  // 0..127 (8-col group)
    int c0 = c8*8;
    u16x8 o;
    #pragma unroll
    for (int j=0;j<8;j+=2){
      float2 v = {0.f, 0.f};
      if (rv && (c0 + j + 1) < G)      v = *(const float2*)(xr + c0 + j);
      else if (rv && (c0 + j) < G)     v.x = xr[c0 + j];
      o[j]   = f2h(v.x);
      o[j+1] = f2h(v.y);
    }
    int t  = c8 >> 2;
    int gg = c8 & 3;
    int l  = rr*4 + gg;
    *(u16x8*)(P + ((size_t)(m*32 + t))*4096 + q*512 + l*8) = o;
  }
}

// ---- CSR build ----
__global__ void count_kernel(const int* __restrict__ dst, int* __restrict__ cnt, int E){
  int e = blockIdx.x*256 + threadIdx.x;
  if (e < E) atomicAdd(&cnt[dst[e]], 1);
}

__global__ void scan_reduce(const int* __restrict__ cnt, int* __restrict__ bsum, int N){
  __shared__ int s[256];
  int tid = threadIdx.x;
  int i = blockIdx.x*256 + tid;
  s[tid] = (i<N)? cnt[i] : 0;
  __syncthreads();
  for (int off=128; off>0; off>>=1){
    if (tid < off) s[tid] += s[tid+off];
    __syncthreads();
  }
  if (tid==0) bsum[blockIdx.x] = s[0];
}

__global__ void scan_offsets(const int* __restrict__ bsum, int* __restrict__ boff, int nb){
  __shared__ int s[256];
  int tid = threadIdx.x;
  int v = (tid<nb)? bsum[tid] : 0;
  s[tid] = v; __syncthreads();
  for (int off=1; off<256; off<<=1){
    int t = (tid>=off)? s[tid-off] : 0;
    __syncthreads();
    s[tid] += t;
    __syncthreads();
  }
  if (tid<nb) boff[tid] = s[tid]-v;
}

__global__ void scan_final(const int* __restrict__ cnt, const int* __restrict__ boff,
                           int* __restrict__ row_ptr, float* __restrict__ dinv, int N, int E){
  __shared__ int s[256];
  int tid = threadIdx.x;
  int i = blockIdx.x*256 + tid;
  int v = (i<N)? cnt[i] : 0;
  s[tid] = v; __syncthreads();
  for (int off=1; off<256; off<<=1){
    int t = (tid>=off)? s[tid-off] : 0;
    __syncthreads();
    s[tid] += t;
    __syncthreads();
  }
  if (i < N){
    row_ptr[i] = boff[blockIdx.x] + s[tid] - v;
    dinv[i] = rsqrtf((float)(v+1));
  }
  if (i == N-1) row_ptr[N] = E;
}

__global__ void scatter_kernel(const int* __restrict__ src, const int* __restrict__ dst,
                               const int* __restrict__ row_ptr, int* __restrict__ cursor,
                               int* __restrict__ colx, int E){
  int e = blockIdx.x*256 + threadIdx.x;
  if (e < E){
    int d = dst[e];
    int pos = atomicAdd(&cursor[d], 1);
    colx[row_ptr[d] + pos] = src[e];
  }
}

// ---- GEMM: C[M x 256] = A @ B^T, 1 wave per 64x64 tile, NO LDS, NO barriers ----
// A: packed chunks (ASTRIDE=4096: 128-row pack_x chunks; 2048: 64-row chunks).
// B: packed 64-row chunks (from transpose_weights).
// Per K-step: 8 fully-coalesced 1KB loads direct to fragment regs + 16 MFMA.
// Register double-buffered (named bufs a0/b0/a1/b1 -> no scratch), compiler
// inserts counted vmcnt (no barrier ever drains it).
// CPACK: write C in packed-64 layout (consumer is the next gemm).
template<int ASTRIDE, bool CPACK, bool ADD_BIAS>
__global__ __launch_bounds__(64) void gemm64(
    const u16* __restrict__ A, const u16* __restrict__ B,
    u16* __restrict__ C, const float* __restrict__ bias, int M, int NT)
{
  const int lane = threadIdx.x & 63;
  const int quad = lane >> 4;
  const int l16  = lane & 15;
  const int m64  = blockIdx.y;
  const int nblk = blockIdx.x;
  const int la   = (l16*4 + quad) * 8;    // u16 offset of this lane's 16B granule

  const u16* Ap = (ASTRIDE == 4096)
      ? A + (size_t)(m64 >> 1) * NT * 4096 + (m64 & 1) * 2048 + la
      : A + (size_t)m64 * NT * 2048 + la;
  const u16* Bp = B + (size_t)nblk * NT * 2048 + la;

  f32x4 acc[4][4];
  #pragma unroll
  for (int i=0;i<4;i++)
    #pragma unroll
    for (int j=0;j<4;j++) acc[i][j] = {0.f,0.f,0.f,0.f};

  f16x8 a0[4], b0[4], a1[4], b1[4];

  auto LD = [&](f16x8* fa, f16x8* fb){
    #pragma unroll
    for (int i=0;i<4;i++) fa[i] = *(const f16x8*)(Ap + i*512);
    #pragma unroll
    for (int i=0;i<4;i++) fb[i] = *(const f16x8*)(Bp + i*512);
    Ap += ASTRIDE;
    Bp += 2048;
  };
  auto CP = [&](const f16x8* fa, const f16x8* fb){
    #pragma unroll
    for (int mt=0;mt<4;mt++)
      #pragma unroll
      for (int nt=0;nt<4;nt++)
        acc[mt][nt] = __builtin_amdgcn_mfma_f32_16x16x32_f16(fa[mt], fb[nt], acc[mt][nt], 0, 0, 0);
  };

  LD(a0, b0);
  for (int t=0; t+2 < NT; t+=2){
    LD(a1, b1); CP(a0, b0);
    LD(a0, b0); CP(a1, b1);
  }
  LD(a1, b1); CP(a0, b0); CP(a1, b1);

  float bv[4];
  if constexpr (ADD_BIAS){
    #pragma unroll
    for (int nt=0;nt<4;nt++) bv[nt] = bias[nblk*64 + nt*16 + l16];
  }

  if constexpr (CPACK){
    // packed-64 C (256 cols -> NTC=8 chunks per m64 block); pad rows written
    // with finite garbage (harmless: A rows only affect same C rows downstream)
    #pragma unroll
    for (int mt=0;mt<4;mt++){
      #pragma unroll
      for (int nt=0;nt<4;nt++){
        int tcol = nblk*2 + (nt>>1);
        int gg   = (nt*2 + (l16>>3)) & 3;
        int e    = l16 & 7;
        #pragma unroll
        for (int r=0;r<4;r++){
          int rr = quad*4 + r;
          size_t idx = ((size_t)m64*8 + tcol)*2048 + mt*512 + (rr*4+gg)*8 + e;
          float v = acc[mt][nt][r];
          if constexpr (ADD_BIAS) v += bv[nt];
          C[idx] = f2h(v);
        }
      }
    }
  } else {
    #pragma unroll
    for (int mt=0;mt<4;mt++){
      #pragma unroll
      for (int nt=0;nt<4;nt++){
        int col = nblk*64 + nt*16 + l16;
        #pragma unroll
        for (int r=0;r<4;r++){
          int row = m64*64 + mt*16 + quad*4 + r;
          float v = acc[mt][nt][r];
          if constexpr (ADD_BIAS) v += bv[nt];
          if (row < M) C[(size_t)row*256 + col] = f2h(v);
        }
      }
    }
  }
}

// ---- GCN aggregation: H[i] = relu( sum_e dinv[s]*dinv[i]*XW[s] + dinv[i]^2*XW[i] + b ) ----
// Reads XW row-major; writes packed-64 chunks (consumer is the next gemm).
__global__ __launch_bounds__(256) void agg_kernel(
    const u16* __restrict__ XW, const float* __restrict__ bias,
    const float* __restrict__ dinv, const int* __restrict__ row_ptr,
    const int* __restrict__ colx, u16* __restrict__ Hp, int N)
{
  int wid = (blockIdx.x << 2) + (threadIdx.x >> 6);
  if (wid >= N) return;
  int lane = threadIdx.x & 63;
  int f = lane << 2;
  float di = dinv[wid];
  int e0 = row_ptr[wid], e1 = row_ptr[wid+1];
  int deg = e1 - e0;
  float a0=0.f, a1=0.f, a2=0.f, a3=0.f;
  for (int base = 0; base < deg; base += 64){
    int mi = 0;
    if (base + lane < deg) mi = colx[e0 + base + lane];
    int cnt = min(deg - base, 64);
    int j = 0;
    for (; j+1 < cnt; j += 2){
      int s0 = __shfl(mi, j);
      int s1 = __shfl(mi, j+1);
      float w0 = dinv[s0]*di;
      float w1 = dinv[s1]*di;
      u16x4 x0 = *(const u16x4*)(XW + (size_t)s0*256 + f);
      u16x4 x1 = *(const u16x4*)(XW + (size_t)s1*256 + f);
      a0 += w0*h2f(x0[0]) + w1*h2f(x1[0]);
      a1 += w0*h2f(x0[1]) + w1*h2f(x1[1]);
      a2 += w0*h2f(x0[2]) + w1*h2f(x1[2]);
      a3 += w0*h2f(x0[3]) + w1*h2f(x1[3]);
    }
    if (j < cnt){
      int s0 = __shfl(mi, j);
      float w0 = dinv[s0]*di;
      u16x4 x0 = *(const u16x4*)(XW + (size_t)s0*256 + f);
      a0 += w0*h2f(x0[0]); a1 += w0*h2f(x0[1]);
      a2 += w0*h2f(x0[2]); a3 += w0*h2f(x0[3]);
    }
  }
  u16x4 xs = *(const u16x4*)(XW + (size_t)wid*256 + f);
  float wd = di*di;
  a0 += wd*h2f(xs[0]); a1 += wd*h2f(xs[1]); a2 += wd*h2f(xs[2]); a3 += wd*h2f(xs[3]);
  const float4 bb = *(const float4*)(bias + f);
  a0 = fmaxf(a0 + bb.x, 0.f);
  a1 = fmaxf(a1 + bb.y, 0.f);
  a2 = fmaxf(a2 + bb.z, 0.f);
  a3 = fmaxf(a3 + bb.w, 0.f);
  u16x4 o = { f2h(a0), f2h(a1), f2h(a2), f2h(a3) };
  // packed-64 write: row=wid, cols f..f+3
  int t  = f >> 5;
  int gg = (f >> 3) & 3;
  int e  = f & 7;                         // 0 or 4
  int rr = wid & 15, q = (wid >> 4) & 3, m64 = wid >> 6;
  size_t idx = ((size_t)m64*8 + t)*2048 + q*512 + (rr*4+gg)*8 + e;
  *(u16x4*)(Hp + idx) = o;
}

// ---- BN stats over axis 0 (row-major input) ----
__global__ void bn_stats(const u16* __restrict__ H, float* __restrict__ bsum,
                         float* __restrict__ bsq, int N){
  int col = threadIdx.x;
  float s=0.f, q=0.f;
  for (int r=blockIdx.x; r<N; r+=gridDim.x){
    float v = h2f(H[(size_t)r*256 + col]);
    s += v; q += v*v;
  }
  atomicAdd(&bsum[col], s);
  atomicAdd(&bsq[col], q);
}

__global__ void bn_finalize(const float* __restrict__ bsum, const float* __restrict__ bsq,
                            const float* __restrict__ gamma, const float* __restrict__ beta,
                            float* __restrict__ scale, float* __restrict__ shift, int N){
  int c = threadIdx.x;
  float invN = 1.f/(float)N;
  float mu  = bsum[c]*invN;
  float var = bsq[c]*invN - mu*mu;
  float sc  = gamma[c] * rsqrtf(var + 1e-5f);
  scale[c] = sc;
  shift[c] = beta[c] - mu*sc;
}

// ---- BN-apply + relu + mlp2 + softmax (row-major input) ----
__global__ __launch_bounds__(256) void final_kernel(
    const u16* __restrict__ H, const float* __restrict__ scale, const float* __restrict__ shift,
    const float* __restrict__ W2, const float* __restrict__ b2, float* __restrict__ out, int N)
{
  __shared__ float W2s[256*20];
  __shared__ float scs[256];
  __shared__ float shs[256];
  __shared__ float b2s[20];
  int tid = threadIdx.x;
  for (int i=tid; i<5120; i+=256) W2s[i] = W2[i];
  scs[tid] = scale[tid];
  shs[tid] = shift[tid];
  if (tid < 20) b2s[tid] = b2[tid];
  __syncthreads();
  int r = blockIdx.x*256 + tid;
  if (r >= N) return;
  float l[20];
  #pragma unroll
  for (int c=0;c<20;c++) l[c] = b2s[c];
  const u16* hrow = H + (size_t)r*256;
  for (int j0=0;j0<256;j0+=8){
    u16x8 h8 = *(const u16x8*)(hrow + j0);
    #pragma unroll
    for (int t=0;t<8;t++){
      int j = j0+t;
      float a = fmaxf(fmaf(h2f(h8[t]), scs[j], shs[j]), 0.f);
      const float* wr = W2s + j*20;
      #pragma unroll
      for (int c=0;c<20;c++) l[c] = fmaf(a, wr[c], l[c]);
    }
  }
  float m = l[0];
  #pragma unroll
  for (int c=1;c<20;c++) m = fmaxf(m, l[c]);
  float ssum = 0.f;
  #pragma unroll
  for (int c=0;c<20;c++){ l[c] = __expf(l[c]-m); ssum += l[c]; }
  float inv = 1.f/ssum;
  float* orow = out + (size_t)r*20;
  #pragma unroll
  for (int c=0;c<20;c++) orow[c] = l[c]*inv;
}

extern "C" void kernel_launch(void* const* d_in, const int* in_sizes, int n_in,
                              void* d_out, int out_size, void* d_ws, size_t ws_size,
                              hipStream_t stream)
{
  (void)n_in; (void)out_size; (void)ws_size;
  const float* x     = (const float*)d_in[0];
  const int*   ei    = (const int*)d_in[1];
  const float* lin_w = (const float*)d_in[2];
  const float* c1w   = (const float*)d_in[3];
  const float* c1b   = (const float*)d_in[4];
  const float* c2w   = (const float*)d_in[5];
  const float* c2b   = (const float*)d_in[6];
  const float* m1w   = (const float*)d_in[7];
  const float* m1b   = (const float*)d_in[8];
  const float* gam   = (const float*)d_in[9];
  const float* bet   = (const float*)d_in[10];
  const float* m2w   = (const float*)d_in[11];
  const float* m2b   = (const float*)d_in[12];
  float* out = (float*)d_out;

  const int E = in_sizes[1]/2;
  const int G = in_sizes[2]/256;          // 1002
  const int N = in_sizes[0]/G;            // 50000
  const int Gpad = (G + 31) & ~31;        // 1024
  const int MB128 = (N + 127) >> 7;       // 391
  const int M64   = (N + 63) >> 6;        // 782
  const int* srcI = ei;
  const int* dstI = ei + E;

  char* w = (char*)d_ws;
  auto alloc = [&](size_t bytes)->char*{
    char* p = w;
    w += (bytes + 255) & ~(size_t)255;
    return p;
  };
  u16* Hpack = (u16*)alloc((size_t)M64*8*2048*2);      // packed-64 H
  u16* Hrow  = (u16*)alloc((size_t)N*256*2);           // row-major H
  u16* packA = (u16*)alloc((size_t)MB128*128*Gpad*2);  // packed-128 x
  u16* linP  = (u16*)alloc((size_t)4*(Gpad>>5)*2048*2);
  u16* w1P   = (u16*)alloc((size_t)4*8*2048*2);
  u16* w2P   = (u16*)alloc((size_t)4*8*2048*2);
  u16* w3P   = (u16*)alloc((size_t)4*8*2048*2);
  int* cnt    = (int*)alloc((size_t)N*4);
  int* cursor = (int*)alloc((size_t)N*4);
  int* rowp   = (int*)alloc((size_t)(N+1)*4);
  int* colx   = (int*)alloc((size_t)E*4);
  float* dinv = (float*)alloc((size_t)N*4);
  int* bsum   = (int*)alloc(1024);
  int* boff   = (int*)alloc(1024);
  float* bnsum= (float*)alloc(1024);
  float* bnsq = (float*)alloc(1024);
  float* scl  = (float*)alloc(1024);
  float* shf  = (float*)alloc(1024);

  hipMemsetAsync(cnt,    0, (size_t)N*4, stream);
  hipMemsetAsync(cursor, 0, (size_t)N*4, stream);
  hipMemsetAsync(bnsum,  0, 2048, stream);               // bnsum + bnsq (contiguous)

  const int NB = (N + 255)/256;

  transpose_weights<<<dim3(8, Gpad>>5, 4), 256, 0, stream>>>(
      lin_w, c1w, c2w, m1w, linP, w1P, w2P, w3P, G, Gpad);
  pack_x<<<dim3(MB128*16), 256, 0, stream>>>(x, packA, N, G);
  count_kernel  <<<dim3((E+255)/256), 256, 0, stream>>>(dstI, cnt, E);
  scan_reduce   <<<dim3(NB), 256, 0, stream>>>(cnt, bsum, N);
  scan_offsets  <<<dim3(1),  256, 0, stream>>>(bsum, boff, NB);
  scan_final    <<<dim3(NB), 256, 0, stream>>>(cnt, boff, rowp, dinv, N, E);
  scatter_kernel<<<dim3((E+255)/256), 256, 0, stream>>>(srcI, dstI, rowp, cursor, colx, E);

  dim3 ggrid(4, M64);
  // encoder linear: x @ lin_w  (A=pack128, C=packed)
  gemm64<4096, true,  false><<<ggrid, 64, 0, stream>>>(packA, linP, Hpack, nullptr, N, Gpad>>5);
  // conv1: (h @ c1w) then aggregate
  gemm64<2048, false, false><<<ggrid, 64, 0, stream>>>(Hpack, w1P, Hrow, nullptr, N, 8);
  agg_kernel<<<dim3((N+3)/4), 256, 0, stream>>>(Hrow, c1b, dinv, rowp, colx, Hpack, N);
  // conv2
  gemm64<2048, false, false><<<ggrid, 64, 0, stream>>>(Hpack, w2P, Hrow, nullptr, N, 8);
  agg_kernel<<<dim3((N+3)/4), 256, 0, stream>>>(Hrow, c2b, dinv, rowp, colx, Hpack, N);
  // decoder linear 1 (+bias), row-major out for BN/final
  gemm64<2048, false, true ><<<ggrid, 64, 0, stream>>>(Hpack, w3P, Hrow, m1b, N, 8);
  bn_stats   <<<dim3(256), 256, 0, stream>>>(Hrow, bnsum, bnsq, N);
  bn_finalize<<<dim3(1),   256, 0, stream>>>(bnsum, bnsq, gam, bet, scl, shf, N);
  final_kernel<<<dim3(NB), 256, 0, stream>>>(Hrow, scl, shf, m2w, m2b, out, N);
}

// Round 7
// 725.554 us; speedup vs baseline: 1.0737x; 1.0737x over previous
//
#include <hip/hip_runtime.h>
#include <cstdint>
#include <cstddef>

typedef unsigned short u16;
typedef unsigned int   u32;
typedef _Float16       f16;
typedef u16  u16x4 __attribute__((ext_vector_type(4)));
typedef u16  u16x8 __attribute__((ext_vector_type(8)));
typedef f16  f16x8 __attribute__((ext_vector_type(8)));
typedef float f32x4 __attribute__((ext_vector_type(4)));

static __device__ __forceinline__ u16 f2h(float f){
  f16 h = (f16)f;
  return __builtin_bit_cast(u16, h);
}
static __device__ __forceinline__ float h2f(u16 b){
  f16 h = __builtin_bit_cast(f16, b);
  return (float)h;
}

// async global->LDS, 16B per lane. lds base must be wave-uniform; HW adds lane*16.
// The GLOBAL address is per-lane.
static __device__ __forceinline__ void async16(void* lds, const void* g){
  __builtin_amdgcn_global_load_lds(
      (const __attribute__((address_space(1))) u32*)g,
      (__attribute__((address_space(3))) u32*)lds, 16, 0, 0);
}

// ---- transpose 4 weight matrices (fp32 in) -> fp16 out, K-contiguous ----
__global__ void transpose_weights(const float* __restrict__ lw, const float* __restrict__ w1,
                                  const float* __restrict__ w2, const float* __restrict__ w3,
                                  u16* __restrict__ lwT, u16* __restrict__ w1T,
                                  u16* __restrict__ w2T, u16* __restrict__ w3T,
                                  int G, int Gpad)
{
  __shared__ float t[32][33];
  int z = blockIdx.z;
  const float* in = (z==0)? lw : (z==1)? w1 : (z==2)? w2 : w3;
  u16* out        = (z==0)? lwT: (z==1)? w1T: (z==2)? w2T: w3T;
  int R   = (z==0)? G : 256;
  int ldo = (z==0)? Gpad : 256;
  int by = blockIdx.y, bx = blockIdx.x;
  if (by*32 >= R && z != 0) return;       // z==0 must still zero-fill pad rows
  int tid = threadIdx.x;
  #pragma unroll
  for (int k=0;k<4;k++){
    int p = tid + k*256; int r = p>>5, c = p&31;
    int gr = by*32 + r;
    t[r][c] = (gr < R) ? in[gr*256 + bx*32 + c] : 0.f;
  }
  __syncthreads();
  #pragma unroll
  for (int k=0;k<4;k++){
    int p = tid + k*256; int r = p>>5, c = p&31;
    int oc = by*32 + c;
    if (oc < ldo) out[(bx*32 + r)*ldo + oc] = f2h(t[c][r]);
  }
}

// ---- cast x (fp32 [N x G]) -> fp16 row-major [N x Gpad], zero-padded ----
// Fully coalesced both sides: thread reads 32B row-contiguous (4x float2,
// 8B-aligned since row stride 4008B), writes one 16B-aligned u16x8.
__global__ __launch_bounds__(256) void cast_x(
    const float* __restrict__ x, u16* __restrict__ xh, int N, int G, int Gpad)
{
  int tid = threadIdx.x;
  int r   = blockIdx.x*2 + (tid >> 7);
  int c0  = (tid & 127) * 8;
  if (r >= N) return;
  const float* xr = x + (size_t)r*G;
  u16x8 o;
  if (c0 + 8 <= G){
    #pragma unroll
    for (int k=0;k<4;k++){
      float2 v = *(const float2*)(xr + c0 + k*2);
      o[k*2]   = f2h(v.x);
      o[k*2+1] = f2h(v.y);
    }
  } else {
    #pragma unroll
    for (int j=0;j<8;j++){
      int c = c0 + j;
      o[j] = (c < G) ? f2h(xr[c]) : (u16)0;
    }
  }
  *(u16x8*)(xh + (size_t)r*Gpad + c0) = o;
}

// ---- CSR build ----
__global__ void count_kernel(const int* __restrict__ dst, int* __restrict__ cnt, int E){
  int e = blockIdx.x*256 + threadIdx.x;
  if (e < E) atomicAdd(&cnt[dst[e]], 1);
}

__global__ void scan_reduce(const int* __restrict__ cnt, int* __restrict__ bsum, int N){
  __shared__ int s[256];
  int tid = threadIdx.x;
  int i = blockIdx.x*256 + tid;
  s[tid] = (i<N)? cnt[i] : 0;
  __syncthreads();
  for (int off=128; off>0; off>>=1){
    if (tid < off) s[tid] += s[tid+off];
    __syncthreads();
  }
  if (tid==0) bsum[blockIdx.x] = s[0];
}

__global__ void scan_offsets(const int* __restrict__ bsum, int* __restrict__ boff, int nb){
  __shared__ int s[256];
  int tid = threadIdx.x;
  int v = (tid<nb)? bsum[tid] : 0;
  s[tid] = v; __syncthreads();
  for (int off=1; off<256; off<<=1){
    int t = (tid>=off)? s[tid-off] : 0;
    __syncthreads();
    s[tid] += t;
    __syncthreads();
  }
  if (tid<nb) boff[tid] = s[tid]-v;
}

__global__ void scan_final(const int* __restrict__ cnt, const int* __restrict__ boff,
                           int* __restrict__ row_ptr, float* __restrict__ dinv, int N, int E){
  __shared__ int s[256];
  int tid = threadIdx.x;
  int i = blockIdx.x*256 + tid;
  int v = (i<N)? cnt[i] : 0;
  s[tid] = v; __syncthreads();
  for (int off=1; off<256; off<<=1){
    int t = (tid>=off)? s[tid-off] : 0;
    __syncthreads();
    s[tid] += t;
    __syncthreads();
  }
  if (i < N){
    row_ptr[i] = boff[blockIdx.x] + s[tid] - v;
    dinv[i] = rsqrtf((float)(v+1));
  }
  if (i == N-1) row_ptr[N] = E;
}

__global__ void scatter_kernel(const int* __restrict__ src, const int* __restrict__ dst,
                               const int* __restrict__ row_ptr, int* __restrict__ cursor,
                               int* __restrict__ colx, int E){
  int e = blockIdx.x*256 + threadIdx.x;
  if (e < E){
    int d = dst[e];
    int pos = atomicAdd(&cursor[d], 1);
    colx[row_ptr[d] + pos] = src[e];
  }
}

// ---- GEMM: C[M x 256] = A @ BT^T, fp16 MFMA ----
// Double-buffered LDS + counted-vmcnt 2-phase pipeline (proven structure).
// A fp16 [M x Kpad] row-major, zero-padded cols. BT fp16 [256 x Kpad], padded.
// XOR swizzle applied to the GLOBAL source column (staging dest is lane*16):
//   fp16 rows (4x16B granules): slot s holds data group s ^ ((row>>1)&3)
template<bool ADD_BIAS>
__global__ __launch_bounds__(256) void gemm_async(
    const u16* __restrict__ Ah,
    const u16* __restrict__ BT, int Kpad,
    u16* __restrict__ C, const float* __restrict__ bias, int M)
{
  __shared__ __align__(16) u16 As[2][4096];
  __shared__ __align__(16) u16 Bs[2][4096];

  const int tid  = threadIdx.x;
  const int lane = tid & 63;
  const int quad = lane >> 4;
  const int l16  = lane & 15;
  const int wave = tid >> 6;
  const int wm = (wave >> 1) << 6;
  const int wn = (wave & 1) << 6;
  const int m0 = blockIdx.y << 7;
  const int n0 = blockIdx.x << 7;

  // staging: chunk q = wave*2+i covers rows q*16..+15.
  const u16* bg[2]; u16* lB[2];
  const u16* ag[2]; u16* lA[2];
  #pragma unroll
  for (int i=0;i<2;i++){
    int q = wave*2 + i;
    int rr = lane >> 2, ss = lane & 3;
    int gg = ss ^ ((rr >> 1) & 3);
    bg[i] = BT + (size_t)(n0 + q*16 + rr)*Kpad + gg*8;
    lB[i] = &Bs[0][0] + q*512;
    int gr = m0 + q*16 + rr;
    if (gr >= M) gr = M-1;
    ag[i] = Ah + (size_t)gr*Kpad + gg*8;
    lA[i] = &As[0][0] + q*512;
  }

  auto stage = [&](int buf, int t){
    const int kb = t << 5;
    #pragma unroll
    for (int i=0;i<2;i++) async16(lB[i] + buf*4096, bg[i] + kb);
    #pragma unroll
    for (int i=0;i<2;i++) async16(lA[i] + buf*4096, ag[i] + kb);
  };

  f32x4 acc[4][4];
  #pragma unroll
  for (int i=0;i<4;i++)
    #pragma unroll
    for (int j=0;j<4;j++) acc[i][j] = {0.f,0.f,0.f,0.f};

  const int NT = Kpad >> 5;

  stage(0, 0);
  int cur = 0;
  for (int t=0; t<NT; ++t){
    if (t+1 < NT){
      stage(cur^1, t+1);
      // next tile's 4 loads stay in flight; wait only for current tile's
      asm volatile("s_waitcnt vmcnt(4)" ::: "memory");
    } else {
      asm volatile("s_waitcnt vmcnt(0)" ::: "memory");
    }
    __builtin_amdgcn_s_barrier();

    const u16* AshC = &As[cur][0];
    const u16* BsC  = &Bs[cur][0];

    f16x8 af[4], bf[4];
    #pragma unroll
    for (int mt=0;mt<4;mt++){
      int R = wm + mt*16 + l16;
      int s = quad ^ ((R >> 1) & 3);
      af[mt] = __builtin_bit_cast(f16x8, *(const u16x8*)(AshC + R*32 + s*8));
    }
    #pragma unroll
    for (int nt=0;nt<4;nt++){
      int R = wn + nt*16 + l16;
      int s = quad ^ ((R >> 1) & 3);
      bf[nt] = __builtin_bit_cast(f16x8, *(const u16x8*)(BsC + R*32 + s*8));
    }
    #pragma unroll
    for (int mt=0;mt<4;mt++)
      #pragma unroll
      for (int nt=0;nt<4;nt++)
        acc[mt][nt] = __builtin_amdgcn_mfma_f32_16x16x32_f16(af[mt], bf[nt], acc[mt][nt], 0, 0, 0);

    __builtin_amdgcn_s_barrier();   // release buf[cur] for restaging next iteration
    cur ^= 1;
  }

  #pragma unroll
  for (int mt=0;mt<4;mt++){
    #pragma unroll
    for (int nt=0;nt<4;nt++){
      int col = n0 + wn + nt*16 + l16;
      float bv = 0.f;
      if constexpr (ADD_BIAS) bv = bias[col];
      #pragma unroll
      for (int r=0;r<4;r++){
        int row = m0 + wm + mt*16 + quad*4 + r;
        if (row < M) C[(size_t)row*256 + col] = f2h(acc[mt][nt][r] + bv);
      }
    }
  }
}

// ---- GCN aggregation: H[i] = relu( sum_e dinv[s]*dinv[i]*XW[s] + dinv[i]^2*XW[i] + b ) ----
__global__ __launch_bounds__(256) void agg_kernel(
    const u16* __restrict__ XW, const float* __restrict__ bias,
    const float* __restrict__ dinv, const int* __restrict__ row_ptr,
    const int* __restrict__ colx, u16* __restrict__ H, int N)
{
  int wid = (blockIdx.x << 2) + (threadIdx.x >> 6);
  if (wid >= N) return;
  int lane = threadIdx.x & 63;
  int f = lane << 2;
  float di = dinv[wid];
  int e0 = row_ptr[wid], e1 = row_ptr[wid+1];
  int deg = e1 - e0;
  float a0=0.f, a1=0.f, a2=0.f, a3=0.f;
  for (int base = 0; base < deg; base += 64){
    int mi = 0;
    if (base + lane < deg) mi = colx[e0 + base + lane];
    int cnt = min(deg - base, 64);
    int j = 0;
    for (; j+1 < cnt; j += 2){
      int s0 = __shfl(mi, j);
      int s1 = __shfl(mi, j+1);
      float w0 = dinv[s0]*di;
      float w1 = dinv[s1]*di;
      u16x4 x0 = *(const u16x4*)(XW + (size_t)s0*256 + f);
      u16x4 x1 = *(const u16x4*)(XW + (size_t)s1*256 + f);
      a0 += w0*h2f(x0[0]) + w1*h2f(x1[0]);
      a1 += w0*h2f(x0[1]) + w1*h2f(x1[1]);
      a2 += w0*h2f(x0[2]) + w1*h2f(x1[2]);
      a3 += w0*h2f(x0[3]) + w1*h2f(x1[3]);
    }
    if (j < cnt){
      int s0 = __shfl(mi, j);
      float w0 = dinv[s0]*di;
      u16x4 x0 = *(const u16x4*)(XW + (size_t)s0*256 + f);
      a0 += w0*h2f(x0[0]); a1 += w0*h2f(x0[1]);
      a2 += w0*h2f(x0[2]); a3 += w0*h2f(x0[3]);
    }
  }
  u16x4 xs = *(const u16x4*)(XW + (size_t)wid*256 + f);
  float wd = di*di;
  a0 += wd*h2f(xs[0]); a1 += wd*h2f(xs[1]); a2 += wd*h2f(xs[2]); a3 += wd*h2f(xs[3]);
  const float4 bb = *(const float4*)(bias + f);
  a0 = fmaxf(a0 + bb.x, 0.f);
  a1 = fmaxf(a1 + bb.y, 0.f);
  a2 = fmaxf(a2 + bb.z, 0.f);
  a3 = fmaxf(a3 + bb.w, 0.f);
  u16x4 o = { f2h(a0), f2h(a1), f2h(a2), f2h(a3) };
  *(u16x4*)(H + (size_t)wid*256 + f) = o;
}

// ---- BN stats over axis 0 ----
__global__ void bn_stats(const u16* __restrict__ H, float* __restrict__ bsum,
                         float* __restrict__ bsq, int N){
  int col = threadIdx.x;
  float s=0.f, q=0.f;
  for (int r=blockIdx.x; r<N; r+=gridDim.x){
    float v = h2f(H[(size_t)r*256 + col]);
    s += v; q += v*v;
  }
  atomicAdd(&bsum[col], s);
  atomicAdd(&bsq[col], q);
}

__global__ void bn_finalize(const float* __restrict__ bsum, const float* __restrict__ bsq,
                            const float* __restrict__ gamma, const float* __restrict__ beta,
                            float* __restrict__ scale, float* __restrict__ shift, int N){
  int c = threadIdx.x;
  float invN = 1.f/(float)N;
  float mu  = bsum[c]*invN;
  float var = bsq[c]*invN - mu*mu;
  float sc  = gamma[c] * rsqrtf(var + 1e-5f);
  scale[c] = sc;
  shift[c] = beta[c] - mu*sc;
}

// ---- BN-apply + relu + mlp2 + softmax ----
__global__ __launch_bounds__(256) void final_kernel(
    const u16* __restrict__ H, const float* __restrict__ scale, const float* __restrict__ shift,
    const float* __restrict__ W2, const float* __restrict__ b2, float* __restrict__ out, int N)
{
  __shared__ float W2s[256*20];
  __shared__ float scs[256];
  __shared__ float shs[256];
  __shared__ float b2s[20];
  int tid = threadIdx.x;
  for (int i=tid; i<5120; i+=256) W2s[i] = W2[i];
  scs[tid] = scale[tid];
  shs[tid] = shift[tid];
  if (tid < 20) b2s[tid] = b2[tid];
  __syncthreads();
  int r = blockIdx.x*256 + tid;
  if (r >= N) return;
  float l[20];
  #pragma unroll
  for (int c=0;c<20;c++) l[c] = b2s[c];
  const u16* hrow = H + (size_t)r*256;
  for (int j0=0;j0<256;j0+=8){
    u16x8 h8 = *(const u16x8*)(hrow + j0);
    #pragma unroll
    for (int t=0;t<8;t++){
      int j = j0+t;
      float a = fmaxf(fmaf(h2f(h8[t]), scs[j], shs[j]), 0.f);
      const float* wr = W2s + j*20;
      #pragma unroll
      for (int c=0;c<20;c++) l[c] = fmaf(a, wr[c], l[c]);
    }
  }
  float m = l[0];
  #pragma unroll
  for (int c=1;c<20;c++) m = fmaxf(m, l[c]);
  float ssum = 0.f;
  #pragma unroll
  for (int c=0;c<20;c++){ l[c] = __expf(l[c]-m); ssum += l[c]; }
  float inv = 1.f/ssum;
  float* orow = out + (size_t)r*20;
  #pragma unroll
  for (int c=0;c<20;c++) orow[c] = l[c]*inv;
}

extern "C" void kernel_launch(void* const* d_in, const int* in_sizes, int n_in,
                              void* d_out, int out_size, void* d_ws, size_t ws_size,
                              hipStream_t stream)
{
  (void)n_in; (void)out_size; (void)ws_size;
  const float* x     = (const float*)d_in[0];
  const int*   ei    = (const int*)d_in[1];
  const float* lin_w = (const float*)d_in[2];
  const float* c1w   = (const float*)d_in[3];
  const float* c1b   = (const float*)d_in[4];
  const float* c2w   = (const float*)d_in[5];
  const float* c2b   = (const float*)d_in[6];
  const float* m1w   = (const float*)d_in[7];
  const float* m1b   = (const float*)d_in[8];
  const float* gam   = (const float*)d_in[9];
  const float* bet   = (const float*)d_in[10];
  const float* m2w   = (const float*)d_in[11];
  const float* m2b   = (const float*)d_in[12];
  float* out = (float*)d_out;

  const int E = in_sizes[1]/2;
  const int G = in_sizes[2]/256;          // 1002
  const int N = in_sizes[0]/G;            // 50000
  const int Gpad = (G + 31) & ~31;        // 1024
  const int* srcI = ei;
  const int* dstI = ei + E;

  char* w = (char*)d_ws;
  auto alloc = [&](size_t bytes)->char*{
    char* p = w;
    w += (bytes + 255) & ~(size_t)255;
    return p;
  };
  u16* Ha    = (u16*)alloc((size_t)N*256*2);
  u16* Hb    = (u16*)alloc((size_t)N*256*2);
  u16* xh    = (u16*)alloc((size_t)N*Gpad*2);
  u16* linT  = (u16*)alloc((size_t)256*Gpad*2);
  u16* w1T   = (u16*)alloc(256*256*2);
  u16* w2T   = (u16*)alloc(256*256*2);
  u16* w3T   = (u16*)alloc(256*256*2);
  int* cnt    = (int*)alloc((size_t)N*4);
  int* cursor = (int*)alloc((size_t)N*4);
  int* rowp   = (int*)alloc((size_t)(N+1)*4);
  int* colx   = (int*)alloc((size_t)E*4);
  float* dinv = (float*)alloc((size_t)N*4);
  int* bsum   = (int*)alloc(1024);
  int* boff   = (int*)alloc(1024);
  float* bnsum= (float*)alloc(1024);
  float* bnsq = (float*)alloc(1024);
  float* scl  = (float*)alloc(1024);
  float* shf  = (float*)alloc(1024);

  hipMemsetAsync(cnt,    0, (size_t)N*4, stream);
  hipMemsetAsync(cursor, 0, (size_t)N*4, stream);
  hipMemsetAsync(bnsum,  0, 2048, stream);               // bnsum + bnsq (contiguous)

  const int NB = (N + 255)/256;

  transpose_weights<<<dim3(8, Gpad>>5, 4), 256, 0, stream>>>(
      lin_w, c1w, c2w, m1w, linT, w1T, w2T, w3T, G, Gpad);
  cast_x<<<dim3((N+1)/2), 256, 0, stream>>>(x, xh, N, G, Gpad);
  count_kernel  <<<dim3((E+255)/256), 256, 0, stream>>>(dstI, cnt, E);
  scan_reduce   <<<dim3(NB), 256, 0, stream>>>(cnt, bsum, N);
  scan_offsets  <<<dim3(1),  256, 0, stream>>>(bsum, boff, NB);
  scan_final    <<<dim3(NB), 256, 0, stream>>>(cnt, boff, rowp, dinv, N, E);
  scatter_kernel<<<dim3((E+255)/256), 256, 0, stream>>>(srcI, dstI, rowp, cursor, colx, E);

  dim3 ggrid(2, (N+127)/128);
  gemm_async<false><<<ggrid, 256, 0, stream>>>(xh, linT, Gpad, Ha, nullptr, N);
  gemm_async<false><<<ggrid, 256, 0, stream>>>(Ha, w1T,  256,  Hb, nullptr, N);
  agg_kernel<<<dim3((N+3)/4), 256, 0, stream>>>(Hb, c1b, dinv, rowp, colx, Ha, N);
  gemm_async<false><<<ggrid, 256, 0, stream>>>(Ha, w2T,  256,  Hb, nullptr, N);
  agg_kernel<<<dim3((N+3)/4), 256, 0, stream>>>(Hb, c2b, dinv, rowp, colx, Ha, N);
  gemm_async<true ><<<ggrid, 256, 0, stream>>>(Ha, w3T,  256,  Hb, m1b, N);
  bn_stats   <<<dim3(256), 256, 0, stream>>>(Hb, bnsum, bnsq, N);
  bn_finalize<<<dim3(1),   256, 0, stream>>>(bnsum, bnsq, gam, bet, scl, shf, N);
  final_kernel<<<dim3(NB), 256, 0, stream>>>(Hb, scl, shf, m2w, m2b, out, N);
}

// Round 8
// 706.925 us; speedup vs baseline: 1.1020x; 1.0264x over previous
//
#include <hip/hip_runtime.h>
#include <cstdint>
#include <cstddef>

typedef unsigned short u16;
typedef unsigned int   u32;
typedef _Float16       f16;
typedef u16  u16x4 __attribute__((ext_vector_type(4)));
typedef u16  u16x8 __attribute__((ext_vector_type(8)));
typedef f16  f16x8 __attribute__((ext_vector_type(8)));
typedef float f32x4 __attribute__((ext_vector_type(4)));

static __device__ __forceinline__ u16 f2h(float f){
  f16 h = (f16)f;
  return __builtin_bit_cast(u16, h);
}
static __device__ __forceinline__ float h2f(u16 b){
  f16 h = __builtin_bit_cast(f16, b);
  return (float)h;
}

// async global->LDS, 16B per lane. lds base must be wave-uniform; HW adds lane*16.
// The GLOBAL address is per-lane.
static __device__ __forceinline__ void async16(void* lds, const void* g){
  __builtin_amdgcn_global_load_lds(
      (const __attribute__((address_space(1))) u32*)g,
      (__attribute__((address_space(3))) u32*)lds, 16, 0, 0);
}

// ---- transpose 3 weight matrices (fp32 [256x256] in) -> fp16 BT layout ----
// wT[col][k] = w[k][col]
__global__ void transpose_weights(const float* __restrict__ w1, const float* __restrict__ w2,
                                  const float* __restrict__ w3,
                                  u16* __restrict__ w1T, u16* __restrict__ w2T,
                                  u16* __restrict__ w3T)
{
  __shared__ float t[32][33];
  int z = blockIdx.z;
  const float* in = (z==0)? w1 : (z==1)? w2 : w3;
  u16* out        = (z==0)? w1T: (z==1)? w2T: w3T;
  int by = blockIdx.y, bx = blockIdx.x;
  int tid = threadIdx.x;
  #pragma unroll
  for (int k=0;k<4;k++){
    int p = tid + k*256; int r = p>>5, c = p&31;
    t[r][c] = in[(by*32 + r)*256 + bx*32 + c];
  }
  __syncthreads();
  #pragma unroll
  for (int k=0;k<4;k++){
    int p = tid + k*256; int r = p>>5, c = p&31;
    out[(bx*32 + r)*256 + by*32 + c] = f2h(t[c][r]);
  }
}

// ---- cast fp32 [N x G] -> fp16 row-major [Npad x Gpad], zero-padded both dims ----
// Fully coalesced: thread reads up to 32B row-contiguous (float2, 8B-aligned),
// writes one 16B-aligned u16x8.
__global__ __launch_bounds__(256) void cast_pad(
    const float* __restrict__ x, u16* __restrict__ xh, int N, int Npad, int G, int Gpad)
{
  int tid = threadIdx.x;
  int tpr = Gpad >> 3;                    // threads per row
  int r   = blockIdx.x*(256/tpr) + tid/tpr;
  if (r >= Npad) return;
  int c0  = (tid % tpr) * 8;
  u16x8 o;
  if (r >= N){
    #pragma unroll
    for (int j=0;j<8;j++) o[j] = 0;
  } else {
    const float* xr = x + (size_t)r*G;
    if (c0 + 8 <= G){
      #pragma unroll
      for (int k=0;k<4;k++){
        float2 v = *(const float2*)(xr + c0 + k*2);
        o[k*2]   = f2h(v.x);
        o[k*2+1] = f2h(v.y);
      }
    } else {
      #pragma unroll
      for (int j=0;j<8;j++){
        int c = c0 + j;
        o[j] = (c < G) ? f2h(xr[c]) : (u16)0;
      }
    }
  }
  *(u16x8*)(xh + (size_t)r*Gpad + c0) = o;
}

// ---- CSR build ----
__global__ void count_kernel(const int* __restrict__ dst, int* __restrict__ cnt, int E){
  int e = blockIdx.x*256 + threadIdx.x;
  if (e < E) atomicAdd(&cnt[dst[e]], 1);
}

__global__ void scan_reduce(const int* __restrict__ cnt, int* __restrict__ bsum, int N){
  __shared__ int s[256];
  int tid = threadIdx.x;
  int i = blockIdx.x*256 + tid;
  s[tid] = (i<N)? cnt[i] : 0;
  __syncthreads();
  for (int off=128; off>0; off>>=1){
    if (tid < off) s[tid] += s[tid+off];
    __syncthreads();
  }
  if (tid==0) bsum[blockIdx.x] = s[0];
}

__global__ void scan_offsets(const int* __restrict__ bsum, int* __restrict__ boff, int nb){
  __shared__ int s[256];
  int tid = threadIdx.x;
  int v = (tid<nb)? bsum[tid] : 0;
  s[tid] = v; __syncthreads();
  for (int off=1; off<256; off<<=1){
    int t = (tid>=off)? s[tid-off] : 0;
    __syncthreads();
    s[tid] += t;
    __syncthreads();
  }
  if (tid<nb) boff[tid] = s[tid]-v;
}

__global__ void scan_final(const int* __restrict__ cnt, const int* __restrict__ boff,
                           int* __restrict__ row_ptr, float* __restrict__ dinv, int N, int E){
  __shared__ int s[256];
  int tid = threadIdx.x;
  int i = blockIdx.x*256 + tid;
  int v = (i<N)? cnt[i] : 0;
  s[tid] = v; __syncthreads();
  for (int off=1; off<256; off<<=1){
    int t = (tid>=off)? s[tid-off] : 0;
    __syncthreads();
    s[tid] += t;
    __syncthreads();
  }
  if (i < N){
    row_ptr[i] = boff[blockIdx.x] + s[tid] - v;
    dinv[i] = rsqrtf((float)(v+1));
  }
  if (i == N-1) row_ptr[N] = E;
}

__global__ void scatter_kernel(const int* __restrict__ src, const int* __restrict__ dst,
                               const int* __restrict__ row_ptr, int* __restrict__ cursor,
                               int* __restrict__ colx, int E){
  int e = blockIdx.x*256 + threadIdx.x;
  if (e < E){
    int d = dst[e];
    int pos = atomicAdd(&cursor[d], 1);
    colx[row_ptr[d] + pos] = src[e];
  }
}

// ---- GEMM: C[M x 256] = A @ BT^T, fp16 MFMA ----
// Double-buffered LDS + counted-vmcnt 2-phase pipeline (proven structure).
// A fp16 [M x Kpad] row-major, zero-padded cols. BT fp16 [256 x Kpad], padded.
// XOR swizzle applied to the GLOBAL source column (staging dest is lane*16):
//   fp16 rows (4x16B granules): slot s holds data group s ^ ((row>>1)&3)
// STORE_T: write C transposed (C[col*ldc + row]) for producing BT-layout outputs.
template<bool ADD_BIAS, bool STORE_T>
__global__ __launch_bounds__(256) void gemm_async(
    const u16* __restrict__ Ah,
    const u16* __restrict__ BT, int Kpad,
    u16* __restrict__ C, const float* __restrict__ bias, int M, int ldc)
{
  __shared__ __align__(16) u16 As[2][4096];
  __shared__ __align__(16) u16 Bs[2][4096];

  const int tid  = threadIdx.x;
  const int lane = tid & 63;
  const int quad = lane >> 4;
  const int l16  = lane & 15;
  const int wave = tid >> 6;
  const int wm = (wave >> 1) << 6;
  const int wn = (wave & 1) << 6;
  const int m0 = blockIdx.y << 7;
  const int n0 = blockIdx.x << 7;

  // staging: chunk q = wave*2+i covers rows q*16..+15.
  const u16* bg[2]; u16* lB[2];
  const u16* ag[2]; u16* lA[2];
  #pragma unroll
  for (int i=0;i<2;i++){
    int q = wave*2 + i;
    int rr = lane >> 2, ss = lane & 3;
    int gg = ss ^ ((rr >> 1) & 3);
    bg[i] = BT + (size_t)(n0 + q*16 + rr)*Kpad + gg*8;
    lB[i] = &Bs[0][0] + q*512;
    int gr = m0 + q*16 + rr;
    if (gr >= M) gr = M-1;
    ag[i] = Ah + (size_t)gr*Kpad + gg*8;
    lA[i] = &As[0][0] + q*512;
  }

  auto stage = [&](int buf, int t){
    const int kb = t << 5;
    #pragma unroll
    for (int i=0;i<2;i++) async16(lB[i] + buf*4096, bg[i] + kb);
    #pragma unroll
    for (int i=0;i<2;i++) async16(lA[i] + buf*4096, ag[i] + kb);
  };

  f32x4 acc[4][4];
  #pragma unroll
  for (int i=0;i<4;i++)
    #pragma unroll
    for (int j=0;j<4;j++) acc[i][j] = {0.f,0.f,0.f,0.f};

  const int NT = Kpad >> 5;

  stage(0, 0);
  int cur = 0;
  for (int t=0; t<NT; ++t){
    if (t+1 < NT){
      stage(cur^1, t+1);
      // next tile's 4 loads stay in flight; wait only for current tile's
      asm volatile("s_waitcnt vmcnt(4)" ::: "memory");
    } else {
      asm volatile("s_waitcnt vmcnt(0)" ::: "memory");
    }
    __builtin_amdgcn_s_barrier();

    const u16* AshC = &As[cur][0];
    const u16* BsC  = &Bs[cur][0];

    f16x8 af[4], bf[4];
    #pragma unroll
    for (int mt=0;mt<4;mt++){
      int R = wm + mt*16 + l16;
      int s = quad ^ ((R >> 1) & 3);
      af[mt] = __builtin_bit_cast(f16x8, *(const u16x8*)(AshC + R*32 + s*8));
    }
    #pragma unroll
    for (int nt=0;nt<4;nt++){
      int R = wn + nt*16 + l16;
      int s = quad ^ ((R >> 1) & 3);
      bf[nt] = __builtin_bit_cast(f16x8, *(const u16x8*)(BsC + R*32 + s*8));
    }
    #pragma unroll
    for (int mt=0;mt<4;mt++)
      #pragma unroll
      for (int nt=0;nt<4;nt++)
        acc[mt][nt] = __builtin_amdgcn_mfma_f32_16x16x32_f16(af[mt], bf[nt], acc[mt][nt], 0, 0, 0);

    __builtin_amdgcn_s_barrier();   // release buf[cur] for restaging next iteration
    cur ^= 1;
  }

  if constexpr (STORE_T){
    #pragma unroll
    for (int mt=0;mt<4;mt++){
      #pragma unroll
      for (int nt=0;nt<4;nt++){
        int col  = n0 + wn + nt*16 + l16;
        int row0 = m0 + wm + mt*16 + quad*4;
        u16x4 o;
        #pragma unroll
        for (int r=0;r<4;r++) o[r] = f2h(acc[mt][nt][r]);
        if (row0 < M) *(u16x4*)(C + (size_t)col*ldc + row0) = o;
      }
    }
  } else {
    #pragma unroll
    for (int mt=0;mt<4;mt++){
      #pragma unroll
      for (int nt=0;nt<4;nt++){
        int col = n0 + wn + nt*16 + l16;
        float bv = 0.f;
        if constexpr (ADD_BIAS) bv = bias[col];
        #pragma unroll
        for (int r=0;r<4;r++){
          int row = m0 + wm + mt*16 + quad*4 + r;
          if (row < M) C[(size_t)row*256 + col] = f2h(acc[mt][nt][r] + bv);
        }
      }
    }
  }
}

// ---- GCN aggregation: H[i] = relu( sum_e dinv[s]*dinv[i]*XW[s] + dinv[i]^2*XW[i] + b ) ----
// 4-way unrolled gather (dependent-load latency is the bottleneck).
__global__ __launch_bounds__(256) void agg_kernel(
    const u16* __restrict__ XW, const float* __restrict__ bias,
    const float* __restrict__ dinv, const int* __restrict__ row_ptr,
    const int* __restrict__ colx, u16* __restrict__ H, int N)
{
  int wid = (blockIdx.x << 2) + (threadIdx.x >> 6);
  if (wid >= N) return;
  int lane = threadIdx.x & 63;
  int f = lane << 2;
  float di = dinv[wid];
  int e0 = row_ptr[wid], e1 = row_ptr[wid+1];
  int deg = e1 - e0;
  float a0=0.f, a1=0.f, a2=0.f, a3=0.f;
  for (int base = 0; base < deg; base += 64){
    int mi = 0;
    if (base + lane < deg) mi = colx[e0 + base + lane];
    int cnt = min(deg - base, 64);
    int j = 0;
    for (; j+3 < cnt; j += 4){
      int s0 = __shfl(mi, j);
      int s1 = __shfl(mi, j+1);
      int s2 = __shfl(mi, j+2);
      int s3 = __shfl(mi, j+3);
      float w0 = dinv[s0]*di;
      float w1 = dinv[s1]*di;
      float w2 = dinv[s2]*di;
      float w3 = dinv[s3]*di;
      u16x4 x0 = *(const u16x4*)(XW + (size_t)s0*256 + f);
      u16x4 x1 = *(const u16x4*)(XW + (size_t)s1*256 + f);
      u16x4 x2 = *(const u16x4*)(XW + (size_t)s2*256 + f);
      u16x4 x3 = *(const u16x4*)(XW + (size_t)s3*256 + f);
      a0 += w0*h2f(x0[0]) + w1*h2f(x1[0]) + w2*h2f(x2[0]) + w3*h2f(x3[0]);
      a1 += w0*h2f(x0[1]) + w1*h2f(x1[1]) + w2*h2f(x2[1]) + w3*h2f(x3[1]);
      a2 += w0*h2f(x0[2]) + w1*h2f(x1[2]) + w2*h2f(x2[2]) + w3*h2f(x3[2]);
      a3 += w0*h2f(x0[3]) + w1*h2f(x1[3]) + w2*h2f(x2[3]) + w3*h2f(x3[3]);
    }
    for (; j < cnt; ++j){
      int s0 = __shfl(mi, j);
      float w0 = dinv[s0]*di;
      u16x4 x0 = *(const u16x4*)(XW + (size_t)s0*256 + f);
      a0 += w0*h2f(x0[0]); a1 += w0*h2f(x0[1]);
      a2 += w0*h2f(x0[2]); a3 += w0*h2f(x0[3]);
    }
  }
  u16x4 xs = *(const u16x4*)(XW + (size_t)wid*256 + f);
  float wd = di*di;
  a0 += wd*h2f(xs[0]); a1 += wd*h2f(xs[1]); a2 += wd*h2f(xs[2]); a3 += wd*h2f(xs[3]);
  const float4 bb = *(const float4*)(bias + f);
  a0 = fmaxf(a0 + bb.x, 0.f);
  a1 = fmaxf(a1 + bb.y, 0.f);
  a2 = fmaxf(a2 + bb.z, 0.f);
  a3 = fmaxf(a3 + bb.w, 0.f);
  u16x4 o = { f2h(a0), f2h(a1), f2h(a2), f2h(a3) };
  *(u16x4*)(H + (size_t)wid*256 + f) = o;
}

// ---- BN stats over axis 0 ----
__global__ void bn_stats(const u16* __restrict__ H, float* __restrict__ bsum,
                         float* __restrict__ bsq, int N){
  int col = threadIdx.x;
  float s=0.f, q=0.f;
  for (int r=blockIdx.x; r<N; r+=gridDim.x){
    float v = h2f(H[(size_t)r*256 + col]);
    s += v; q += v*v;
  }
  atomicAdd(&bsum[col], s);
  atomicAdd(&bsq[col], q);
}

__global__ void bn_finalize(const float* __restrict__ bsum, const float* __restrict__ bsq,
                            const float* __restrict__ gamma, const float* __restrict__ beta,
                            float* __restrict__ scale, float* __restrict__ shift, int N){
  int c = threadIdx.x;
  float invN = 1.f/(float)N;
  float mu  = bsum[c]*invN;
  float var = bsq[c]*invN - mu*mu;
  float sc  = gamma[c] * rsqrtf(var + 1e-5f);
  scale[c] = sc;
  shift[c] = beta[c] - mu*sc;
}

// ---- BN-apply + relu + mlp2 + softmax ----
__global__ __launch_bounds__(256) void final_kernel(
    const u16* __restrict__ H, const float* __restrict__ scale, const float* __restrict__ shift,
    const float* __restrict__ W2, const float* __restrict__ b2, float* __restrict__ out, int N)
{
  __shared__ float W2s[256*20];
  __shared__ float scs[256];
  __shared__ float shs[256];
  __shared__ float b2s[20];
  int tid = threadIdx.x;
  for (int i=tid; i<5120; i+=256) W2s[i] = W2[i];
  scs[tid] = scale[tid];
  shs[tid] = shift[tid];
  if (tid < 20) b2s[tid] = b2[tid];
  __syncthreads();
  int r = blockIdx.x*256 + tid;
  if (r >= N) return;
  float l[20];
  #pragma unroll
  for (int c=0;c<20;c++) l[c] = b2s[c];
  const u16* hrow = H + (size_t)r*256;
  for (int j0=0;j0<256;j0+=8){
    u16x8 h8 = *(const u16x8*)(hrow + j0);
    #pragma unroll
    for (int t=0;t<8;t++){
      int j = j0+t;
      float a = fmaxf(fmaf(h2f(h8[t]), scs[j], shs[j]), 0.f);
      const float* wr = W2s + j*20;
      #pragma unroll
      for (int c=0;c<20;c++) l[c] = fmaf(a, wr[c], l[c]);
    }
  }
  float m = l[0];
  #pragma unroll
  for (int c=1;c<20;c++) m = fmaxf(m, l[c]);
  float ssum = 0.f;
  #pragma unroll
  for (int c=0;c<20;c++){ l[c] = __expf(l[c]-m); ssum += l[c]; }
  float inv = 1.f/ssum;
  float* orow = out + (size_t)r*20;
  #pragma unroll
  for (int c=0;c<20;c++) orow[c] = l[c]*inv;
}

extern "C" void kernel_launch(void* const* d_in, const int* in_sizes, int n_in,
                              void* d_out, int out_size, void* d_ws, size_t ws_size,
                              hipStream_t stream)
{
  (void)n_in; (void)out_size; (void)ws_size;
  const float* x     = (const float*)d_in[0];
  const int*   ei    = (const int*)d_in[1];
  const float* lin_w = (const float*)d_in[2];
  const float* c1w   = (const float*)d_in[3];
  const float* c1b   = (const float*)d_in[4];
  const float* c2w   = (const float*)d_in[5];
  const float* c2b   = (const float*)d_in[6];
  const float* m1w   = (const float*)d_in[7];
  const float* m1b   = (const float*)d_in[8];
  const float* gam   = (const float*)d_in[9];
  const float* bet   = (const float*)d_in[10];
  const float* m2w   = (const float*)d_in[11];
  const float* m2b   = (const float*)d_in[12];
  float* out = (float*)d_out;

  const int E = in_sizes[1]/2;
  const int G = in_sizes[2]/256;          // 1002
  const int N = in_sizes[0]/G;            // 50000
  const int Gpad = (G + 31) & ~31;        // 1024
  const int* srcI = ei;
  const int* dstI = ei + E;

  char* w = (char*)d_ws;
  auto alloc = [&](size_t bytes)->char*{
    char* p = w;
    w += (bytes + 255) & ~(size_t)255;
    return p;
  };
  u16* Ha    = (u16*)alloc((size_t)N*256*2);
  u16* Hb    = (u16*)alloc((size_t)N*256*2);
  u16* xh    = (u16*)alloc((size_t)N*Gpad*2);
  u16* linH  = (u16*)alloc((size_t)Gpad*256*2);   // lin_w fp16 [Gpad x 256], row-padded
  u16* BT1   = (u16*)alloc((size_t)256*Gpad*2);   // (lin_w @ c1w)^T, BT layout
  u16* w1T   = (u16*)alloc(256*256*2);
  u16* w2T   = (u16*)alloc(256*256*2);
  u16* w3T   = (u16*)alloc(256*256*2);
  int* cnt    = (int*)alloc((size_t)N*4);
  int* cursor = (int*)alloc((size_t)N*4);
  int* rowp   = (int*)alloc((size_t)(N+1)*4);
  int* colx   = (int*)alloc((size_t)E*4);
  float* dinv = (float*)alloc((size_t)N*4);
  int* bsum   = (int*)alloc(1024);
  int* boff   = (int*)alloc(1024);
  float* bnsum= (float*)alloc(1024);
  float* bnsq = (float*)alloc(1024);
  float* scl  = (float*)alloc(1024);
  float* shf  = (float*)alloc(1024);

  hipMemsetAsync(cnt,    0, (size_t)N*4, stream);
  hipMemsetAsync(cursor, 0, (size_t)N*4, stream);
  hipMemsetAsync(bnsum,  0, 2048, stream);               // bnsum + bnsq (contiguous)

  const int NB = (N + 255)/256;

  transpose_weights<<<dim3(8, 8, 3), 256, 0, stream>>>(c1w, c2w, m1w, w1T, w2T, w3T);
  // lin_w fp32 [G x 256] -> fp16 [Gpad x 256], rows >= G zeroed
  cast_pad<<<dim3((Gpad+7)/8), 256, 0, stream>>>(lin_w, linH, G, Gpad, 256, 256);
  // x fp32 [N x G] -> fp16 [N x Gpad], cols >= G zeroed
  cast_pad<<<dim3((N+1)/2), 256, 0, stream>>>(x, xh, N, N, G, Gpad);
  // BT1[col][g] = (lin_w @ c1w)[g][col]  (small GEMM, transposed store)
  gemm_async<false, true><<<dim3(2, Gpad/128), 256, 0, stream>>>(
      linH, w1T, 256, BT1, nullptr, Gpad, Gpad);

  count_kernel  <<<dim3((E+255)/256), 256, 0, stream>>>(dstI, cnt, E);
  scan_reduce   <<<dim3(NB), 256, 0, stream>>>(cnt, bsum, N);
  scan_offsets  <<<dim3(1),  256, 0, stream>>>(bsum, boff, NB);
  scan_final    <<<dim3(NB), 256, 0, stream>>>(cnt, boff, rowp, dinv, N, E);
  scatter_kernel<<<dim3((E+255)/256), 256, 0, stream>>>(srcI, dstI, rowp, cursor, colx, E);

  dim3 ggrid(2, (N+127)/128);
  // conv1 XW = x @ (lin_w @ c1w)  — encoder GEMM fused away by associativity
  gemm_async<false, false><<<ggrid, 256, 0, stream>>>(xh, BT1, Gpad, Hb, nullptr, N, 256);
  agg_kernel<<<dim3((N+3)/4), 256, 0, stream>>>(Hb, c1b, dinv, rowp, colx, Ha, N);
  // conv2 XW = h1 @ c2w
  gemm_async<false, false><<<ggrid, 256, 0, stream>>>(Ha, w2T, 256, Hb, nullptr, N, 256);
  agg_kernel<<<dim3((N+3)/4), 256, 0, stream>>>(Hb, c2b, dinv, rowp, colx, Ha, N);
  // decoder linear 1 (+bias)
  gemm_async<true, false><<<ggrid, 256, 0, stream>>>(Ha, w3T, 256, Hb, m1b, N, 256);
  bn_stats   <<<dim3(256), 256, 0, stream>>>(Hb, bnsum, bnsq, N);
  bn_finalize<<<dim3(1),   256, 0, stream>>>(bnsum, bnsq, gam, bet, scl, shf, N);
  final_kernel<<<dim3(NB), 256, 0, stream>>>(Hb, scl, shf, m2w, m2b, out, N);
}

// Round 9
// 649.489 us; speedup vs baseline: 1.1995x; 1.0884x over previous
//
#include <hip/hip_runtime.h>
#include <cstdint>
#include <cstddef>

typedef unsigned short u16;
typedef unsigned int   u32;
typedef _Float16       f16;
typedef u16  u16x4 __attribute__((ext_vector_type(4)));
typedef u16  u16x8 __attribute__((ext_vector_type(8)));
typedef f16  f16x8 __attribute__((ext_vector_type(8)));
typedef float f32x4 __attribute__((ext_vector_type(4)));

static __device__ __forceinline__ u16 f2h(float f){
  f16 h = (f16)f;
  return __builtin_bit_cast(u16, h);
}
static __device__ __forceinline__ float h2f(u16 b){
  f16 h = __builtin_bit_cast(f16, b);
  return (float)h;
}

// async global->LDS, 16B per lane. lds base must be wave-uniform; HW adds lane*16.
// The GLOBAL address is per-lane.
static __device__ __forceinline__ void async16(void* lds, const void* g){
  __builtin_amdgcn_global_load_lds(
      (const __attribute__((address_space(1))) u32*)g,
      (__attribute__((address_space(3))) u32*)lds, 16, 0, 0);
}

// ---- prep: transpose 3 weight matrices (fp32 [256x256] -> fp16 BT layout),
//      plus z==3: cast lin_w fp32 [G x 256] -> fp16 [Gpad x 256] row-major ----
__global__ void prep_weights(const float* __restrict__ lw,
                             const float* __restrict__ w1, const float* __restrict__ w2,
                             const float* __restrict__ w3,
                             u16* __restrict__ linH,
                             u16* __restrict__ w1T, u16* __restrict__ w2T,
                             u16* __restrict__ w3T, int G)
{
  int z = blockIdx.z;
  int tid = threadIdx.x;
  if (z == 3){
    // cast+pad lin_w: 1024 rows x 256 cols fp16, rows >= G zeroed
    int bidx = blockIdx.y*8 + blockIdx.x;     // 0..63
    int base = (bidx*256 + tid)*2;            // u16x8 index, 2 per thread
    #pragma unroll
    for (int i=0;i<2;i++){
      int p = base + i;                       // 0..32767
      int row = p >> 5;
      int c0  = (p & 31) * 8;
      u16x8 o;
      if (row < G){
        const float* xr = lw + (size_t)row*256 + c0;
        #pragma unroll
        for (int k=0;k<4;k++){
          float2 v = *(const float2*)(xr + k*2);
          o[k*2]   = f2h(v.x);
          o[k*2+1] = f2h(v.y);
        }
      } else {
        #pragma unroll
        for (int j=0;j<8;j++) o[j] = 0;
      }
      *(u16x8*)(linH + (size_t)row*256 + c0) = o;
    }
    return;
  }
  __shared__ float t[32][33];
  const float* in = (z==0)? w1 : (z==1)? w2 : w3;
  u16* out        = (z==0)? w1T: (z==1)? w2T: w3T;
  int by = blockIdx.y, bx = blockIdx.x;
  #pragma unroll
  for (int k=0;k<4;k++){
    int p = tid + k*256; int r = p>>5, c = p&31;
    t[r][c] = in[(by*32 + r)*256 + bx*32 + c];
  }
  __syncthreads();
  #pragma unroll
  for (int k=0;k<4;k++){
    int p = tid + k*256; int r = p>>5, c = p&31;
    out[(bx*32 + r)*256 + by*32 + c] = f2h(t[c][r]);
  }
}

// ---- cast x fp32 [N x G] -> fp16 row-major [N x Gpad], zero-padded cols ----
__global__ __launch_bounds__(256) void cast_x(
    const float* __restrict__ x, u16* __restrict__ xh, int N, int G, int Gpad)
{
  int tid = threadIdx.x;
  int r   = blockIdx.x*2 + (tid >> 7);
  if (r >= N) return;
  int c0  = (tid & 127) * 8;
  const float* xr = x + (size_t)r*G;
  u16x8 o;
  if (c0 + 8 <= G){
    #pragma unroll
    for (int k=0;k<4;k++){
      float2 v = *(const float2*)(xr + c0 + k*2);
      o[k*2]   = f2h(v.x);
      o[k*2+1] = f2h(v.y);
    }
  } else {
    #pragma unroll
    for (int j=0;j<8;j++){
      int c = c0 + j;
      o[j] = (c < G) ? f2h(xr[c]) : (u16)0;
    }
  }
  *(u16x8*)(xh + (size_t)r*Gpad + c0) = o;
}

// ---- CSR build ----
__global__ void count_kernel(const int* __restrict__ dst, int* __restrict__ cnt, int E){
  int e = blockIdx.x*256 + threadIdx.x;
  if (e < E) atomicAdd(&cnt[dst[e]], 1);
}

__global__ void scan_reduce(const int* __restrict__ cnt, int* __restrict__ bsum, int N){
  __shared__ int s[256];
  int tid = threadIdx.x;
  int i = blockIdx.x*256 + tid;
  s[tid] = (i<N)? cnt[i] : 0;
  __syncthreads();
  for (int off=128; off>0; off>>=1){
    if (tid < off) s[tid] += s[tid+off];
    __syncthreads();
  }
  if (tid==0) bsum[blockIdx.x] = s[0];
}

__global__ void scan_offsets(const int* __restrict__ bsum, int* __restrict__ boff, int nb){
  __shared__ int s[256];
  int tid = threadIdx.x;
  int v = (tid<nb)? bsum[tid] : 0;
  s[tid] = v; __syncthreads();
  for (int off=1; off<256; off<<=1){
    int t = (tid>=off)? s[tid-off] : 0;
    __syncthreads();
    s[tid] += t;
    __syncthreads();
  }
  if (tid<nb) boff[tid] = s[tid]-v;
}

__global__ void scan_final(const int* __restrict__ cnt, const int* __restrict__ boff,
                           int* __restrict__ row_ptr, float* __restrict__ dinv, int N, int E){
  __shared__ int s[256];
  int tid = threadIdx.x;
  int i = blockIdx.x*256 + tid;
  int v = (i<N)? cnt[i] : 0;
  s[tid] = v; __syncthreads();
  for (int off=1; off<256; off<<=1){
    int t = (tid>=off)? s[tid-off] : 0;
    __syncthreads();
    s[tid] += t;
    __syncthreads();
  }
  if (i < N){
    row_ptr[i] = boff[blockIdx.x] + s[tid] - v;
    dinv[i] = rsqrtf((float)(v+1));
  }
  if (i == N-1) row_ptr[N] = E;
}

__global__ void scatter_kernel(const int* __restrict__ src, const int* __restrict__ dst,
                               const int* __restrict__ row_ptr, int* __restrict__ cursor,
                               int* __restrict__ colx, int E){
  int e = blockIdx.x*256 + threadIdx.x;
  if (e < E){
    int d = dst[e];
    int pos = atomicAdd(&cursor[d], 1);
    colx[row_ptr[d] + pos] = src[e];
  }
}

// ---- GEMM: C[M x 256] = A @ BT^T, fp16 MFMA ----
// Double-buffered LDS + counted-vmcnt 2-phase pipeline (proven structure).
// A fp16 [M x Kpad] row-major, zero-padded cols. BT fp16 [256 x Kpad], padded.
// XOR swizzle applied to the GLOBAL source column (staging dest is lane*16):
//   fp16 rows (4x16B granules): slot s holds data group s ^ ((row>>1)&3)
// STORE_T: write C transposed (C[col*ldc + row]).
// STATS: accumulate per-column sum / sum-of-squares of (acc+bias) over valid
//        rows into bnsum/bnsq (LDS reduce -> 2 atomics per col per block).
template<bool ADD_BIAS, bool STORE_T, bool STATS>
__global__ __launch_bounds__(256) void gemm_async(
    const u16* __restrict__ Ah,
    const u16* __restrict__ BT, int Kpad,
    u16* __restrict__ C, const float* __restrict__ bias, int M, int ldc,
    float* __restrict__ bnsum, float* __restrict__ bnsq)
{
  __shared__ __align__(16) u16 As[2][4096];
  __shared__ __align__(16) u16 Bs[2][4096];

  const int tid  = threadIdx.x;
  const int lane = tid & 63;
  const int quad = lane >> 4;
  const int l16  = lane & 15;
  const int wave = tid >> 6;
  const int wm = (wave >> 1) << 6;
  const int wn = (wave & 1) << 6;
  const int m0 = blockIdx.y << 7;
  const int n0 = blockIdx.x << 7;

  // staging: chunk q = wave*2+i covers rows q*16..+15.
  const u16* bg[2]; u16* lB[2];
  const u16* ag[2]; u16* lA[2];
  #pragma unroll
  for (int i=0;i<2;i++){
    int q = wave*2 + i;
    int rr = lane >> 2, ss = lane & 3;
    int gg = ss ^ ((rr >> 1) & 3);
    bg[i] = BT + (size_t)(n0 + q*16 + rr)*Kpad + gg*8;
    lB[i] = &Bs[0][0] + q*512;
    int gr = m0 + q*16 + rr;
    if (gr >= M) gr = M-1;
    ag[i] = Ah + (size_t)gr*Kpad + gg*8;
    lA[i] = &As[0][0] + q*512;
  }

  auto stage = [&](int buf, int t){
    const int kb = t << 5;
    #pragma unroll
    for (int i=0;i<2;i++) async16(lB[i] + buf*4096, bg[i] + kb);
    #pragma unroll
    for (int i=0;i<2;i++) async16(lA[i] + buf*4096, ag[i] + kb);
  };

  f32x4 acc[4][4];
  #pragma unroll
  for (int i=0;i<4;i++)
    #pragma unroll
    for (int j=0;j<4;j++) acc[i][j] = {0.f,0.f,0.f,0.f};

  const int NT = Kpad >> 5;

  stage(0, 0);
  int cur = 0;
  for (int t=0; t<NT; ++t){
    if (t+1 < NT){
      stage(cur^1, t+1);
      // next tile's 4 loads stay in flight; wait only for current tile's
      asm volatile("s_waitcnt vmcnt(4)" ::: "memory");
    } else {
      asm volatile("s_waitcnt vmcnt(0)" ::: "memory");
    }
    __builtin_amdgcn_s_barrier();

    const u16* AshC = &As[cur][0];
    const u16* BsC  = &Bs[cur][0];

    f16x8 af[4], bf[4];
    #pragma unroll
    for (int mt=0;mt<4;mt++){
      int R = wm + mt*16 + l16;
      int s = quad ^ ((R >> 1) & 3);
      af[mt] = __builtin_bit_cast(f16x8, *(const u16x8*)(AshC + R*32 + s*8));
    }
    #pragma unroll
    for (int nt=0;nt<4;nt++){
      int R = wn + nt*16 + l16;
      int s = quad ^ ((R >> 1) & 3);
      bf[nt] = __builtin_bit_cast(f16x8, *(const u16x8*)(BsC + R*32 + s*8));
    }
    #pragma unroll
    for (int mt=0;mt<4;mt++)
      #pragma unroll
      for (int nt=0;nt<4;nt++)
        acc[mt][nt] = __builtin_amdgcn_mfma_f32_16x16x32_f16(af[mt], bf[nt], acc[mt][nt], 0, 0, 0);

    __builtin_amdgcn_s_barrier();   // release buf[cur] for restaging next iteration
    cur ^= 1;
  }

  float bv[4] = {0.f, 0.f, 0.f, 0.f};
  if constexpr (ADD_BIAS){
    #pragma unroll
    for (int nt=0;nt<4;nt++) bv[nt] = bias[n0 + wn + nt*16 + l16];
  }

  if constexpr (STORE_T){
    #pragma unroll
    for (int mt=0;mt<4;mt++){
      #pragma unroll
      for (int nt=0;nt<4;nt++){
        int col  = n0 + wn + nt*16 + l16;
        int row0 = m0 + wm + mt*16 + quad*4;
        u16x4 o;
        #pragma unroll
        for (int r=0;r<4;r++) o[r] = f2h(acc[mt][nt][r]);
        if (row0 < M) *(u16x4*)(C + (size_t)col*ldc + row0) = o;
      }
    }
  } else {
    #pragma unroll
    for (int mt=0;mt<4;mt++){
      #pragma unroll
      for (int nt=0;nt<4;nt++){
        int col = n0 + wn + nt*16 + l16;
        #pragma unroll
        for (int r=0;r<4;r++){
          int row = m0 + wm + mt*16 + quad*4 + r;
          if (row < M) C[(size_t)row*256 + col] = f2h(acc[mt][nt][r] + bv[nt]);
        }
      }
    }
  }

  if constexpr (STATS){
    // per-column sum / sumsq of (acc+bias) over valid rows, fused BN stats.
    // LDS is free after the final loop barrier; reuse As as float scratch.
    float* ssum = (float*)&As[0][0];      // 128 floats (cols n0..n0+127)
    float* ssq  = ssum + 128;
    if (tid < 128){ ssum[tid] = 0.f; ssq[tid] = 0.f; }
    __syncthreads();
    #pragma unroll
    for (int nt=0;nt<4;nt++){
      float s = 0.f, q = 0.f;
      #pragma unroll
      for (int mt=0;mt<4;mt++){
        #pragma unroll
        for (int r=0;r<4;r++){
          int row = m0 + wm + mt*16 + quad*4 + r;
          if (row < M){
            float v = acc[mt][nt][r] + bv[nt];
            s += v; q += v*v;
          }
        }
      }
      int colL = wn + nt*16 + l16;        // 0..127
      atomicAdd(&ssum[colL], s);
      atomicAdd(&ssq[colL],  q);
    }
    __syncthreads();
    if (tid < 128){
      atomicAdd(&bnsum[n0 + tid], ssum[tid]);
      atomicAdd(&bnsq[n0 + tid],  ssq[tid]);
    }
  }
}

// ---- GCN aggregation: H[i] = relu( sum_e dinv[s]*dinv[i]*XW[s] + dinv[i]^2*XW[i] + b ) ----
__global__ __launch_bounds__(256) void agg_kernel(
    const u16* __restrict__ XW, const float* __restrict__ bias,
    const float* __restrict__ dinv, const int* __restrict__ row_ptr,
    const int* __restrict__ colx, u16* __restrict__ H, int N)
{
  int wid = (blockIdx.x << 2) + (threadIdx.x >> 6);
  if (wid >= N) return;
  int lane = threadIdx.x & 63;
  int f = lane << 2;
  float di = dinv[wid];
  int e0 = row_ptr[wid], e1 = row_ptr[wid+1];
  int deg = e1 - e0;
  float a0=0.f, a1=0.f, a2=0.f, a3=0.f;
  for (int base = 0; base < deg; base += 64){
    int mi = 0;
    if (base + lane < deg) mi = colx[e0 + base + lane];
    int cnt = min(deg - base, 64);
    int j = 0;
    for (; j+3 < cnt; j += 4){
      int s0 = __shfl(mi, j);
      int s1 = __shfl(mi, j+1);
      int s2 = __shfl(mi, j+2);
      int s3 = __shfl(mi, j+3);
      float w0 = dinv[s0]*di;
      float w1 = dinv[s1]*di;
      float w2 = dinv[s2]*di;
      float w3 = dinv[s3]*di;
      u16x4 x0 = *(const u16x4*)(XW + (size_t)s0*256 + f);
      u16x4 x1 = *(const u16x4*)(XW + (size_t)s1*256 + f);
      u16x4 x2 = *(const u16x4*)(XW + (size_t)s2*256 + f);
      u16x4 x3 = *(const u16x4*)(XW + (size_t)s3*256 + f);
      a0 += w0*h2f(x0[0]) + w1*h2f(x1[0]) + w2*h2f(x2[0]) + w3*h2f(x3[0]);
      a1 += w0*h2f(x0[1]) + w1*h2f(x1[1]) + w2*h2f(x2[1]) + w3*h2f(x3[1]);
      a2 += w0*h2f(x0[2]) + w1*h2f(x1[2]) + w2*h2f(x2[2]) + w3*h2f(x3[2]);
      a3 += w0*h2f(x0[3]) + w1*h2f(x1[3]) + w2*h2f(x2[3]) + w3*h2f(x3[3]);
    }
    for (; j < cnt; ++j){
      int s0 = __shfl(mi, j);
      float w0 = dinv[s0]*di;
      u16x4 x0 = *(const u16x4*)(XW + (size_t)s0*256 + f);
      a0 += w0*h2f(x0[0]); a1 += w0*h2f(x0[1]);
      a2 += w0*h2f(x0[2]); a3 += w0*h2f(x0[3]);
    }
  }
  u16x4 xs = *(const u16x4*)(XW + (size_t)wid*256 + f);
  float wd = di*di;
  a0 += wd*h2f(xs[0]); a1 += wd*h2f(xs[1]); a2 += wd*h2f(xs[2]); a3 += wd*h2f(xs[3]);
  const float4 bb = *(const float4*)(bias + f);
  a0 = fmaxf(a0 + bb.x, 0.f);
  a1 = fmaxf(a1 + bb.y, 0.f);
  a2 = fmaxf(a2 + bb.z, 0.f);
  a3 = fmaxf(a3 + bb.w, 0.f);
  u16x4 o = { f2h(a0), f2h(a1), f2h(a2), f2h(a3) };
  *(u16x4*)(H + (size_t)wid*256 + f) = o;
}

// ---- BN-finalize (inline) + BN-apply + relu + mlp2 + softmax ----
__global__ __launch_bounds__(256) void final_kernel(
    const u16* __restrict__ H,
    const float* __restrict__ gamma, const float* __restrict__ beta,
    const float* __restrict__ bnsum, const float* __restrict__ bnsq,
    const float* __restrict__ W2, const float* __restrict__ b2, float* __restrict__ out, int N)
{
  __shared__ float W2s[256*20];
  __shared__ float scs[256];
  __shared__ float shs[256];
  __shared__ float b2s[20];
  int tid = threadIdx.x;
  for (int i=tid; i<5120; i+=256) W2s[i] = W2[i];
  {
    float invN = 1.f/(float)N;
    float mu  = bnsum[tid]*invN;
    float var = bnsq[tid]*invN - mu*mu;
    float sc  = gamma[tid] * rsqrtf(var + 1e-5f);
    scs[tid] = sc;
    shs[tid] = beta[tid] - mu*sc;
  }
  if (tid < 20) b2s[tid] = b2[tid];
  __syncthreads();
  int r = blockIdx.x*256 + tid;
  if (r >= N) return;
  float l[20];
  #pragma unroll
  for (int c=0;c<20;c++) l[c] = b2s[c];
  const u16* hrow = H + (size_t)r*256;
  for (int j0=0;j0<256;j0+=8){
    u16x8 h8 = *(const u16x8*)(hrow + j0);
    #pragma unroll
    for (int t=0;t<8;t++){
      int j = j0+t;
      float a = fmaxf(fmaf(h2f(h8[t]), scs[j], shs[j]), 0.f);
      const float* wr = W2s + j*20;
      #pragma unroll
      for (int c=0;c<20;c++) l[c] = fmaf(a, wr[c], l[c]);
    }
  }
  float m = l[0];
  #pragma unroll
  for (int c=1;c<20;c++) m = fmaxf(m, l[c]);
  float ssum = 0.f;
  #pragma unroll
  for (int c=0;c<20;c++){ l[c] = __expf(l[c]-m); ssum += l[c]; }
  float inv = 1.f/ssum;
  float* orow = out + (size_t)r*20;
  #pragma unroll
  for (int c=0;c<20;c++) orow[c] = l[c]*inv;
}

extern "C" void kernel_launch(void* const* d_in, const int* in_sizes, int n_in,
                              void* d_out, int out_size, void* d_ws, size_t ws_size,
                              hipStream_t stream)
{
  (void)n_in; (void)out_size; (void)ws_size;
  const float* x     = (const float*)d_in[0];
  const int*   ei    = (const int*)d_in[1];
  const float* lin_w = (const float*)d_in[2];
  const float* c1w   = (const float*)d_in[3];
  const float* c1b   = (const float*)d_in[4];
  const float* c2w   = (const float*)d_in[5];
  const float* c2b   = (const float*)d_in[6];
  const float* m1w   = (const float*)d_in[7];
  const float* m1b   = (const float*)d_in[8];
  const float* gam   = (const float*)d_in[9];
  const float* bet   = (const float*)d_in[10];
  const float* m2w   = (const float*)d_in[11];
  const float* m2b   = (const float*)d_in[12];
  float* out = (float*)d_out;

  const int E = in_sizes[1]/2;
  const int G = in_sizes[2]/256;          // 1002
  const int N = in_sizes[0]/G;            // 50000
  const int Gpad = (G + 31) & ~31;        // 1024
  const int* srcI = ei;
  const int* dstI = ei + E;

  char* w = (char*)d_ws;
  auto alloc = [&](size_t bytes)->char*{
    char* p = w;
    w += (bytes + 255) & ~(size_t)255;
    return p;
  };
  u16* Ha    = (u16*)alloc((size_t)N*256*2);
  u16* Hb    = (u16*)alloc((size_t)N*256*2);
  u16* xh    = (u16*)alloc((size_t)N*Gpad*2);
  u16* linH  = (u16*)alloc((size_t)Gpad*256*2);   // lin_w fp16 [Gpad x 256], row-padded
  u16* BT1   = (u16*)alloc((size_t)256*Gpad*2);   // (lin_w @ c1w)^T, BT layout
  u16* w1T   = (u16*)alloc(256*256*2);
  u16* w2T   = (u16*)alloc(256*256*2);
  u16* w3T   = (u16*)alloc(256*256*2);
  const size_t szN = ((size_t)N*4 + 255) & ~(size_t)255;
  int* cnt    = (int*)alloc(szN);                 // cnt + cursor contiguous
  int* cursor = (int*)alloc(szN);
  int* rowp   = (int*)alloc((size_t)(N+1)*4);
  int* colx   = (int*)alloc((size_t)E*4);
  float* dinv = (float*)alloc((size_t)N*4);
  int* bsum   = (int*)alloc(1024);
  int* boff   = (int*)alloc(1024);
  float* bnsum= (float*)alloc(1024);
  float* bnsq = (float*)alloc(1024);

  hipMemsetAsync(cnt,   0, szN*2, stream);        // cnt + cursor in one memset
  hipMemsetAsync(bnsum, 0, 2048, stream);         // bnsum + bnsq (contiguous)

  const int NB = (N + 255)/256;

  // weights prep: 3 transposes + lin_w cast, one launch
  prep_weights<<<dim3(8, 8, 4), 256, 0, stream>>>(
      lin_w, c1w, c2w, m1w, linH, w1T, w2T, w3T, G);
  // x fp32 [N x G] -> fp16 [N x Gpad]
  cast_x<<<dim3((N+1)/2), 256, 0, stream>>>(x, xh, N, G, Gpad);
  // BT1[col][g] = (lin_w @ c1w)[g][col]  (small GEMM, transposed store)
  gemm_async<false, true, false><<<dim3(2, Gpad/128), 256, 0, stream>>>(
      linH, w1T, 256, BT1, nullptr, Gpad, Gpad, nullptr, nullptr);

  count_kernel  <<<dim3((E+255)/256), 256, 0, stream>>>(dstI, cnt, E);
  scan_reduce   <<<dim3(NB), 256, 0, stream>>>(cnt, bsum, N);
  scan_offsets  <<<dim3(1),  256, 0, stream>>>(bsum, boff, NB);
  scan_final    <<<dim3(NB), 256, 0, stream>>>(cnt, boff, rowp, dinv, N, E);
  scatter_kernel<<<dim3((E+255)/256), 256, 0, stream>>>(srcI, dstI, rowp, cursor, colx, E);

  dim3 ggrid(2, (N+127)/128);
  // conv1 XW = x @ (lin_w @ c1w)  — encoder GEMM fused away by associativity
  gemm_async<false, false, false><<<ggrid, 256, 0, stream>>>(
      xh, BT1, Gpad, Hb, nullptr, N, 256, nullptr, nullptr);
  agg_kernel<<<dim3((N+3)/4), 256, 0, stream>>>(Hb, c1b, dinv, rowp, colx, Ha, N);
  // conv2 XW = h1 @ c2w
  gemm_async<false, false, false><<<ggrid, 256, 0, stream>>>(
      Ha, w2T, 256, Hb, nullptr, N, 256, nullptr, nullptr);
  agg_kernel<<<dim3((N+3)/4), 256, 0, stream>>>(Hb, c2b, dinv, rowp, colx, Ha, N);
  // decoder linear 1 (+bias) with fused BN stats
  gemm_async<true, false, true><<<ggrid, 256, 0, stream>>>(
      Ha, w3T, 256, Hb, m1b, N, 256, bnsum, bnsq);
  final_kernel<<<dim3(NB), 256, 0, stream>>>(Hb, gam, bet, bnsum, bnsq, m2w, m2b, out, N);
}